// Round 9
// baseline (13581.725 us; speedup 1.0000x reference)
//
#include <hip/hip_runtime.h>
#include <cmath>

#define HID 150
#define FOURH 600
#define BATCH 64
#define TLEN 2048
#define NB 16     // batches per recur WG
#define NT 40     // M-tiles (640 rows = 160 units x 4 gates, units >=150 pad)
#define NW 8      // waves per recur WG
#define MT 5      // M-tiles per wave
#define NK5 5     // K-tiles of 32 (k padded 150->160)
#define HTS 168   // Ht row stride in f16 elems (bank spread)

typedef _Float16 f16;
typedef __attribute__((ext_vector_type(8))) _Float16 f16x8;
typedef __attribute__((ext_vector_type(4))) float f32x4;

__device__ __forceinline__ float sigmoidf_(float x) {
    return 1.0f / (1.0f + __expf(-x));
}
__device__ __forceinline__ float tanhf_(float x) {
    return 1.0f - 2.0f / (__expf(2.0f * x) + 1.0f);
}

// x_proj[b, i, c] = bias[c] + sum_k X[b, t0+i, k] * Wx[k, c]   (f32, unchanged from r5)
__global__ __launch_bounds__(640, 2) void xproj_gemm(
    const float* __restrict__ X,     // [BATCH, TLEN, 150]
    const float* __restrict__ Wx,    // [150, 600]
    const float* __restrict__ bias,  // [600]
    float* __restrict__ xp,          // [BATCH, C, 600]
    int t0, int C)
{
    const int blocks_per_batch = C / 32;
    const int b  = blockIdx.x / blocks_per_batch;
    const int i0 = (blockIdx.x % blocks_per_batch) * 32;
    const float* Xbase = X + ((size_t)(b * TLEN + t0 + i0)) * HID;

    __shared__ __align__(16) float xt[150 * 36];
    const int tid = threadIdx.x;
    for (int i = tid; i < 32 * HID; i += 640) {
        int r = i / HID, k = i % HID;
        xt[k * 36 + r] = Xbase[(size_t)r * HID + k];
    }
    __syncthreads();

    if (tid < FOURH) {
        float acc[32];
        #pragma unroll
        for (int r = 0; r < 32; ++r) acc[r] = 0.f;
        for (int k = 0; k < HID; ++k) {
            float w = Wx[(size_t)k * FOURH + tid];
            #pragma unroll
            for (int r4 = 0; r4 < 8; ++r4) {
                float4 xv = *(const float4*)&xt[k * 36 + r4 * 4];
                acc[r4*4+0] += xv.x * w;
                acc[r4*4+1] += xv.y * w;
                acc[r4*4+2] += xv.z * w;
                acc[r4*4+3] += xv.w * w;
            }
        }
        float bv = bias[tid];
        float* o = xp + ((size_t)b * C + i0) * FOURH + tid;
        #pragma unroll
        for (int r = 0; r < 32; ++r) o[(size_t)r * FOURH] = acc[r] + bv;
    }
}

// Pack Wh into MFMA A-fragments, unit-interleaved rows (row = 4u+g):
// whm[layer][T][K5][lane][e] (f16), T=M-tile, K5=k-tile, lane holds
// A[row = T*16 + (lane&15)][k = K5*32 + (lane>>4)*8 + e].
__global__ void pack_whm(const float* __restrict__ Wh0,
                         const float* __restrict__ Wh1,
                         f16* __restrict__ dst) {
    int idx = blockIdx.x * 256 + threadIdx.x;
    if (idx >= 2 * 102400) return;
    int layer = idx / 102400, r = idx - layer * 102400;
    int e = r & 7;
    int lane = (r >> 3) & 63;
    int fi = r >> 9;              // T*5 + K5
    int K5 = fi % 5, T = fi / 5;
    int row = T * 16 + (lane & 15);
    int u = row >> 2, g = row & 3;
    int k = K5 * 32 + (lane >> 4) * 8 + e;
    const float* Wh = layer ? Wh1 : Wh0;
    float v = (u < HID && k < HID) ? Wh[(size_t)k * FOURH + g * HID + u] : 0.f;
    dst[idx] = (f16)v;
}

// MFMA recurrence. Grid = (nA+nB)*4 WGs of 512 threads (8 waves).
// WG handles 16 batches, all 600 gates. Wave owns 25 A-frags (weights) in
// registers, loaded ONCE -- 16x in-register reuse per weight byte breaks the
// weight-refetch floor (r1-r7 journal). Stage B is lane-local: C-frag lane
// (q,n) reg ri = gate ri of unit T*4+q, batch b0+n.
__global__ __launch_bounds__(512)
__attribute__((amdgpu_waves_per_eu(2, 2)))
void lstm_recur_mfma(
    int nA, const float* __restrict__ xpA, const f16* __restrict__ whmA,
    float* __restrict__ stA, int t0A,
    const float* __restrict__ xpB, const f16* __restrict__ whmB,
    float* __restrict__ stB, int t0B,
    float* __restrict__ out, int C)
{
    const int w = blockIdx.x;
    const int isB = (w >= nA * 4) ? 1 : 0;
    const float* xp  = isB ? xpB  : xpA;
    const f16*   whm = isB ? whmB : whmA;
    float*     state = isB ? stB  : stA;
    const int  t0    = isB ? t0B  : t0A;
    const int  b0    = (isB ? (w - nA * 4) : w) * NB;

    const int tid = threadIdx.x;
    const int wv = tid >> 6;     // wave 0..7
    const int l  = tid & 63;
    const int q  = l >> 4;       // 0..3
    const int n  = l & 15;       // batch within group

    __shared__ __align__(16) f16 Ht[NB][HTS];

    // ---- one-time: load this wave's 25 weight fragments ----
    f16x8 wf[MT][NK5];
    {
        const f16* base = whm + ((size_t)(wv * MT) * NK5 * 64) * 8 + (size_t)l * 8;
        #pragma unroll
        for (int f = 0; f < MT; ++f)
            #pragma unroll
            for (int k5 = 0; k5 < NK5; ++k5)
                wf[f][k5] = *(const f16x8*)(base + (size_t)(f * NK5 + k5) * 64 * 8);
    }

    // per-lane unit indices + c-state
    int uu[MT];
    float cst[MT];
    #pragma unroll
    for (int f = 0; f < MT; ++f) {
        uu[f] = (wv * MT + f) * 4 + q;
        cst[f] = 0.f;
    }
    if (t0 != 0) {
        #pragma unroll
        for (int f = 0; f < MT; ++f)
            if (uu[f] < HID) cst[f] = state[(b0 + n) * 300 + uu[f]];
    }

    // init Ht (h as f16; tail k>=150 zero)
    for (int x = tid; x < NB * HTS; x += 512) {
        int bn = x / HTS, k = x - bn * HTS;
        float hv = 0.f;
        if (t0 != 0 && k < HID) hv = state[(b0 + bn) * 300 + HID + k];
        Ht[bn][k] = (f16)hv;
    }
    __syncthreads();

    // xp prefetch for step 0
    float xn[MT][4];
    #pragma unroll
    for (int f = 0; f < MT; ++f)
        #pragma unroll
        for (int g = 0; g < 4; ++g)
            xn[f][g] = (uu[f] < HID)
                ? xp[((size_t)(b0 + n) * C) * FOURH + g * HID + uu[f]] : 0.f;

    for (int i = 0; i < C; ++i) {
        // ---- B-frags: H[k 32][n 16] slices, one ds_read_b128 each ----
        f16x8 bf[NK5];
        #pragma unroll
        for (int k5 = 0; k5 < NK5; ++k5)
            bf[k5] = *(const f16x8*)&Ht[n][k5 * 32 + q * 8];
        __syncthreads();   // all reads done before any stage-B Ht write

        // ---- MFMA: acc[f] = sum_k5 A(wf) x B(bf) ----
        f32x4 acc[MT];
        #pragma unroll
        for (int f = 0; f < MT; ++f) {
            f32x4 a = {0.f, 0.f, 0.f, 0.f};
            #pragma unroll
            for (int k5 = 0; k5 < NK5; ++k5)
                a = __builtin_amdgcn_mfma_f32_16x16x32_f16(wf[f][k5], bf[k5], a, 0, 0, 0);
            acc[f] = a;
        }

        // consume prefetched xp, issue next step's prefetch
        float xc[MT][4];
        #pragma unroll
        for (int f = 0; f < MT; ++f)
            #pragma unroll
            for (int g = 0; g < 4; ++g)
                xc[f][g] = xn[f][g];
        if (i + 1 < C) {
            #pragma unroll
            for (int f = 0; f < MT; ++f)
                #pragma unroll
                for (int g = 0; g < 4; ++g)
                    xn[f][g] = (uu[f] < HID)
                        ? xp[((size_t)(b0 + n) * C + (i + 1)) * FOURH + g * HID + uu[f]] : 0.f;
        }

        // ---- stage B: lane-local gates, c/h update ----
        #pragma unroll
        for (int f = 0; f < MT; ++f) {
            float ig = sigmoidf_(acc[f][0] + xc[f][0]);
            float fg = sigmoidf_(acc[f][1] + xc[f][1]);
            float gg = tanhf_  (acc[f][2] + xc[f][2]);
            float og = sigmoidf_(acc[f][3] + xc[f][3]);
            cst[f] = fg * cst[f] + ig * gg;
            float hn = og * tanhf_(cst[f]);
            if (uu[f] < HID) {
                Ht[n][uu[f]] = (f16)hn;
                out[((size_t)(b0 + n) * TLEN + t0 + i) * HID + uu[f]] = hn;
            }
        }
        __syncthreads();   // h_{i+1} visible for next iteration's reads
    }

    // save state
    #pragma unroll
    for (int f = 0; f < MT; ++f)
        if (uu[f] < HID) {
            state[(b0 + n) * 300 + uu[f]] = cst[f];
            state[(b0 + n) * 300 + HID + uu[f]] = (float)Ht[n][uu[f]];
        }
}

extern "C" void kernel_launch(void* const* d_in, const int* in_sizes, int n_in,
                              void* d_out, int out_size, void* d_ws, size_t ws_size,
                              hipStream_t stream) {
    const float* xs  = (const float*)d_in[0];
    const float* Wx0 = (const float*)d_in[1];
    const float* Wh0 = (const float*)d_in[2];
    const float* b0  = (const float*)d_in[3];
    const float* Wx1 = (const float*)d_in[4];
    const float* Wh1 = (const float*)d_in[5];
    const float* b1  = (const float*)d_in[6];
    float* out = (float*)d_out;

    int C = 256;
    {
        size_t need = 2ull * BATCH * C * FOURH * 4 + 2ull * 102400 * 2
                    + 2ull * BATCH * 300 * 4;
        if (need > ws_size) C = 128;
    }
    const size_t xpsz = (size_t)BATCH * C * FOURH * 4;
    char* p = (char*)d_ws;
    float* xp0 = (float*)p; p += xpsz;
    float* xp1 = (float*)p; p += xpsz;
    f16* whm = (f16*)p;     p += 2ull * 102400 * 2;
    float* st0 = (float*)p; p += (size_t)BATCH * 300 * 4;
    float* st1 = (float*)p;
    const f16* whm0 = whm;
    const f16* whm1 = whm + 102400;

    pack_whm<<<dim3((2 * 102400 + 255) / 256), dim3(256), 0, stream>>>(Wh0, Wh1, whm);

    const int nchunk = TLEN / C;
    const int gpb = C / 32;

    // Slot s: xproj(L0,s), xproj(L1,s-1), then recur(L0 s || L1 s-1).
    // Stream order provides all producer->consumer dependencies.
    for (int s = 0; s <= nchunk; ++s) {
        const int hasA = (s < nchunk) ? 1 : 0;
        const int hasB = (s >= 1) ? 1 : 0;
        if (hasA)
            xproj_gemm<<<dim3(BATCH * gpb), dim3(640), 0, stream>>>(
                xs, Wx0, b0, xp0, s * C, C);
        if (hasB)
            xproj_gemm<<<dim3(BATCH * gpb), dim3(640), 0, stream>>>(
                out, Wx1, b1, xp1, (s - 1) * C, C);
        lstm_recur_mfma<<<dim3((hasA + hasB) * 4), dim3(512), 0, stream>>>(
            hasA, xp0, whm0, st0, s * C,
            xp1, whm1, st1, (s - 1) * C,
            out, C);
    }
}

// Round 10
// 2265.088 us; speedup vs baseline: 5.9961x; 5.9961x over previous
//
#include <hip/hip_runtime.h>
#include <cmath>

#define HID 150
#define FOURH 600
#define BATCH 64
#define TLEN 2048
#define NKS 5  // 32-wide k-slices over k padded 150->160

typedef _Float16 f16;
typedef __attribute__((ext_vector_type(2))) _Float16 half2_t;
typedef __attribute__((ext_vector_type(8))) _Float16 f16x8;
typedef __attribute__((ext_vector_type(4))) float f32x4;

#if defined(__has_builtin)
#if __has_builtin(__builtin_amdgcn_fdot2)
#define FDOT2(a, b, c) __builtin_amdgcn_fdot2((a), (b), (c), false)
#endif
#endif
#ifndef FDOT2
__device__ __forceinline__ float fdot2_fb(half2_t a, half2_t b, float c) {
    return c + (float)a.x * (float)b.x + (float)a.y * (float)b.y;
}
#define FDOT2(a, b, c) fdot2_fb((a), (b), (c))
#endif

__device__ __forceinline__ float sigmoidf_(float x) {
    return 1.0f / (1.0f + __expf(-x));
}
__device__ __forceinline__ float tanhf_(float x) {
    return 1.0f - 2.0f / (__expf(2.0f * x) + 1.0f);
}

// ======================= packing kernels =======================

// Wh -> per-thread-sliced half2 (r5 layout):
// whp[layer][ks*9600 + (g*16+p)*150 + j] = (Wh[32ks+2p][g*150+j], Wh[32ks+2p+1][...])
__global__ void pack_wh(const float* __restrict__ Wh0, const float* __restrict__ Wh1,
                        half2_t* __restrict__ whp) {
    int idx = blockIdx.x * 256 + threadIdx.x;
    if (idx >= 2 * 48000) return;
    int layer = idx / 48000, r = idx - layer * 48000;
    int j = r % HID, t = r / HID;       // t = (ks*4+g)*16+p
    int p = t & 15, gks = t >> 4;
    int g = gks & 3, ks = gks >> 2;
    const float* Wh = layer ? Wh1 : Wh0;
    int k0 = ks * 32 + 2 * p;
    float a  = (k0 < HID)     ? Wh[(size_t)k0 * FOURH + g * HID + j]       : 0.f;
    float bb = (k0 + 1 < HID) ? Wh[(size_t)(k0 + 1) * FOURH + g * HID + j] : 0.f;
    half2_t h; h.x = (_Float16)a; h.y = (_Float16)bb;
    whp[idx] = h;
}

// Wx -> MFMA B-frags (layout verified on-device in r9):
// wxp[layer][f=ct*5+k5][lane][e] = Wx[k][n], n=ct*16+(lane&15), k=k5*32+(lane>>4)*8+e
#define WXP_PER_LAYER (38 * 5 * 64 * 8)
__global__ void pack_wxm(const float* __restrict__ Wx0, const float* __restrict__ Wx1,
                         f16* __restrict__ dst) {
    int idx = blockIdx.x * 256 + threadIdx.x;
    if (idx >= 2 * WXP_PER_LAYER) return;
    int layer = idx / WXP_PER_LAYER, r = idx - layer * WXP_PER_LAYER;
    int e = r & 7;
    int lane = (r >> 3) & 63;
    int f = r >> 9;                  // ct*5 + k5
    int k5 = f % 5, ct = f / 5;
    int n = ct * 16 + (lane & 15);
    int k = k5 * 32 + (lane >> 4) * 8 + e;
    const float* Wx = layer ? Wx1 : Wx0;
    float v = (n < FOURH && k < HID) ? Wx[(size_t)k * FOURH + n] : 0.f;
    dst[idx] = (f16)v;
}

// ======================= xproj via MFMA =======================
// One WG (256 thr, 4 waves) = one (batch, 32 time rows) tile of one layer.
// Grid: [nA * 64*(C/32) layer-A WGs | 64*(C/32) layer-B WGs].
__global__ __launch_bounds__(256) void xproj_mfma(
    int nA, const float* __restrict__ XA, const f16* __restrict__ wxA,
    const float* __restrict__ biasA, float* __restrict__ xdA, int tA,
    const float* __restrict__ XB, const f16* __restrict__ wxB,
    const float* __restrict__ biasB, float* __restrict__ xdB, int tB,
    int C)
{
    const int xg = C / 32;
    const int per = 64 * xg;
    int x = blockIdx.x;
    const int isB = (x >= nA * per) ? 1 : 0;
    if (isB) x -= nA * per;
    const float* X    = isB ? XB    : XA;
    const f16*   wx   = isB ? wxB   : wxA;
    const float* bias = isB ? biasB : biasA;
    float*       xd   = isB ? xdB   : xdA;
    const int    t0   = isB ? tB    : tA;

    const int b  = x / xg;
    const int i0 = (x - b * xg) * 32;
    const int tid = threadIdx.x;
    const int wv = tid >> 6;
    const int l  = tid & 63;

    __shared__ __align__(16) f16 Xs[32][168];   // 32 rows x k(0..159), pad->168

    const float* Xbase = X + ((size_t)(b * TLEN + t0 + i0)) * HID;
    #pragma unroll
    for (int it = 0; it < 20; ++it) {
        int idx = tid + it * 256;               // 32*160 = 5120
        int r = idx / 160, k = idx - r * 160;
        Xs[r][k] = (f16)((k < HID) ? Xbase[(size_t)r * HID + k] : 0.f);
    }
    __syncthreads();

    // A-frags: 2 m-tiles x 5 k-tiles, in registers
    f16x8 af[2][NKS];
    #pragma unroll
    for (int mt = 0; mt < 2; ++mt)
        #pragma unroll
        for (int k5 = 0; k5 < NKS; ++k5)
            af[mt][k5] = *(const f16x8*)&Xs[mt * 16 + (l & 15)][k5 * 32 + (l >> 4) * 8];

    const int n_lo = l & 15;
    const int r0 = (l >> 4) * 4;
    for (int ct = wv; ct < 38; ct += 4) {
        const f16* wb = wx + ((size_t)(ct * 5) * 64 + l) * 8;
        f32x4 acc0 = {0.f, 0.f, 0.f, 0.f};
        f32x4 acc1 = {0.f, 0.f, 0.f, 0.f};
        #pragma unroll
        for (int k5 = 0; k5 < NKS; ++k5) {
            f16x8 bf = *(const f16x8*)(wb + (size_t)k5 * 64 * 8);
            acc0 = __builtin_amdgcn_mfma_f32_16x16x32_f16(af[0][k5], bf, acc0, 0, 0, 0);
            acc1 = __builtin_amdgcn_mfma_f32_16x16x32_f16(af[1][k5], bf, acc1, 0, 0, 0);
        }
        const int n = ct * 16 + n_lo;
        if (n < FOURH) {
            float bv = bias[n];
            float* o = xd + ((size_t)b * C + i0) * FOURH + n;
            #pragma unroll
            for (int r = 0; r < 4; ++r) {
                o[(size_t)(r0 + r) * FOURH]      = acc0[r] + bv;
                o[(size_t)(16 + r0 + r) * FOURH] = acc1[r] + bv;
            }
        }
    }
}

// ======================= recurrence (r5 verbatim — best: 0.92us/step) =======================
#define WL(arr, G, P) arr[(P)] = Wj[((G) * 16 + (P)) * HID];
#define WL16(arr, G) WL(arr,G,0) WL(arr,G,1) WL(arr,G,2) WL(arr,G,3) WL(arr,G,4) \
  WL(arr,G,5) WL(arr,G,6) WL(arr,G,7) WL(arr,G,8) WL(arr,G,9) WL(arr,G,10) \
  WL(arr,G,11) WL(arr,G,12) WL(arr,G,13) WL(arr,G,14) WL(arr,G,15)

#define KEEP2(x) do { float _kf = __builtin_bit_cast(float, (x)); \
    asm("" : "+v"(_kf)); (x) = __builtin_bit_cast(half2_t, _kf); } while (0)
#define KEEP4(arr, B) KEEP2(arr[(B)+0]); KEEP2(arr[(B)+1]); KEEP2(arr[(B)+2]); KEEP2(arr[(B)+3]);
#define KEEP16(arr) KEEP4(arr,0) KEEP4(arr,4) KEEP4(arr,8) KEEP4(arr,12)

#define DOTQ(Q) { \
  float4 hv = *(const float4*)(const void*)&h16[ks * 32 + (Q) * 8]; \
  half2_t h0 = __builtin_bit_cast(half2_t, hv.x); \
  half2_t h1 = __builtin_bit_cast(half2_t, hv.y); \
  half2_t h2 = __builtin_bit_cast(half2_t, hv.z); \
  half2_t h3 = __builtin_bit_cast(half2_t, hv.w); \
  a0 = FDOT2(h0, w0[(Q)*4+0], a0); a0 = FDOT2(h1, w0[(Q)*4+1], a0); \
  a0 = FDOT2(h2, w0[(Q)*4+2], a0); a0 = FDOT2(h3, w0[(Q)*4+3], a0); \
  a1 = FDOT2(h0, w1[(Q)*4+0], a1); a1 = FDOT2(h1, w1[(Q)*4+1], a1); \
  a1 = FDOT2(h2, w1[(Q)*4+2], a1); a1 = FDOT2(h3, w1[(Q)*4+3], a1); \
  a2 = FDOT2(h0, w2[(Q)*4+0], a2); a2 = FDOT2(h1, w2[(Q)*4+1], a2); \
  a2 = FDOT2(h2, w2[(Q)*4+2], a2); a2 = FDOT2(h3, w2[(Q)*4+3], a2); \
  a3 = FDOT2(h0, w3[(Q)*4+0], a3); a3 = FDOT2(h1, w3[(Q)*4+1], a3); \
  a3 = FDOT2(h2, w3[(Q)*4+2], a3); a3 = FDOT2(h3, w3[(Q)*4+3], a3); }

__global__ __launch_bounds__(768)
__attribute__((amdgpu_waves_per_eu(3, 3)))
void lstm_recur2(const float* __restrict__ xpA, const half2_t* __restrict__ whpA,
                 float* __restrict__ stA, int t0A,
                 const float* __restrict__ xpB, const half2_t* __restrict__ whpB,
                 float* __restrict__ stB, int t0B,
                 float* __restrict__ out, int C)
{
    const int part = blockIdx.x >> 6;
    const int b = blockIdx.x & 63;
    const int tid = threadIdx.x;
    const int tidc = (tid < 750) ? tid : 749;
    const int ks = tidc / HID;
    const int j  = tidc - ks * HID;

    const float*   xp    = part ? xpB  : xpA;
    const half2_t* whp   = part ? whpB : whpA;
    float*         state = part ? stB  : stA;
    const int      t0    = part ? t0B  : t0A;

    __shared__ __align__(16) _Float16 h16[160];
    __shared__ __align__(16) float part_s[NKS][4][152];

    half2_t w0[16], w1[16], w2[16], w3[16];
    {
        const half2_t* Wj = whp + (size_t)ks * 9600 + j;
        WL16(w0, 0) WL16(w1, 1) WL16(w2, 2) WL16(w3, 3)
    }
    KEEP16(w0) KEEP16(w1) KEEP16(w2) KEEP16(w3)

    float cst = 0.f;
    if (tid < 160) {
        float hv = 0.f;
        if (t0 != 0 && tid < HID) {
            cst = state[b * 300 + tid];
            hv  = state[b * 300 + HID + tid];
        }
        h16[tid] = (_Float16)hv;
    }
    __syncthreads();

    const float* xpb = xp + (size_t)b * C * FOURH;
    float* outb = out + ((size_t)b * TLEN + t0) * HID;

    float xn0 = 0.f, xn1 = 0.f, xn2 = 0.f, xn3 = 0.f;
    if (tid < HID) {
        xn0 = xpb[tid];
        xn1 = xpb[HID + tid];
        xn2 = xpb[2 * HID + tid];
        xn3 = xpb[3 * HID + tid];
    }

    for (int i = 0; i < C; ++i) {
        if (tid < 750) {
            float a0 = 0.f, a1 = 0.f, a2 = 0.f, a3 = 0.f;
            DOTQ(0) DOTQ(1) DOTQ(2) DOTQ(3)
            part_s[ks][0][j] = a0;
            part_s[ks][1][j] = a1;
            part_s[ks][2][j] = a2;
            part_s[ks][3][j] = a3;
        }
        __syncthreads();

        if (tid < HID) {
            float p0 = xn0, p1 = xn1, p2 = xn2, p3 = xn3;
            if (i + 1 < C) {
                const float* p = &xpb[(size_t)(i + 1) * FOURH];
                xn0 = p[tid];
                xn1 = p[HID + tid];
                xn2 = p[2 * HID + tid];
                xn3 = p[3 * HID + tid];
            }
            float z0 = p0, z1 = p1, z2 = p2, z3 = p3;
            #pragma unroll
            for (int s = 0; s < NKS; ++s) {
                z0 += part_s[s][0][tid];
                z1 += part_s[s][1][tid];
                z2 += part_s[s][2][tid];
                z3 += part_s[s][3][tid];
            }
            float ig = sigmoidf_(z0);
            float fg = sigmoidf_(z1);
            float gg = tanhf_(z2);
            float og = sigmoidf_(z3);
            cst = fg * cst + ig * gg;
            float hn = og * tanhf_(cst);
            h16[tid] = (_Float16)hn;
            outb[(size_t)i * HID + tid] = hn;
        }
        __syncthreads();
    }

    if (tid < HID) {
        state[b * 300 + tid] = cst;
        state[b * 300 + HID + tid] = (float)h16[tid];
    }
}

extern "C" void kernel_launch(void* const* d_in, const int* in_sizes, int n_in,
                              void* d_out, int out_size, void* d_ws, size_t ws_size,
                              hipStream_t stream) {
    const float* xs  = (const float*)d_in[0];
    const float* Wx0 = (const float*)d_in[1];
    const float* Wh0 = (const float*)d_in[2];
    const float* b0  = (const float*)d_in[3];
    const float* Wx1 = (const float*)d_in[4];
    const float* Wh1 = (const float*)d_in[5];
    const float* b1  = (const float*)d_in[6];
    float* out = (float*)d_out;

    int C = 256;
    {
        size_t need = 2ull * BATCH * C * FOURH * 4 + 48000ull * 2 * 4
                    + 2ull * WXP_PER_LAYER * 2 + 2ull * BATCH * 300 * 4;
        if (need > ws_size) C = 128;
    }
    const size_t xpsz = (size_t)BATCH * C * FOURH * 4;
    char* p = (char*)d_ws;
    float* xp0 = (float*)p;      p += xpsz;
    float* xp1 = (float*)p;      p += xpsz;
    half2_t* whp = (half2_t*)p;  p += 96000ull * 4;
    f16* wxp = (f16*)p;          p += 2ull * WXP_PER_LAYER * 2;
    float* st0 = (float*)p;      p += (size_t)BATCH * 300 * 4;
    float* st1 = (float*)p;
    const half2_t* whp0 = whp;
    const half2_t* whp1 = whp + 48000;
    const f16* wxp0 = wxp;
    const f16* wxp1 = wxp + WXP_PER_LAYER;

    pack_wh<<<dim3((2 * 48000 + 255) / 256), dim3(256), 0, stream>>>(Wh0, Wh1, whp);
    pack_wxm<<<dim3((2 * WXP_PER_LAYER + 255) / 256), dim3(256), 0, stream>>>(Wx0, Wx1, wxp);

    const int nchunk = TLEN / C;
    const int xg = C / 32;

    // Slot s: xproj(L0 chunk s + L1 chunk s-1) then recur(L0 s || L1 s-1).
    for (int s = 0; s <= nchunk; ++s) {
        const int hasA = (s < nchunk) ? 1 : 0;
        const int hasB = (s >= 1) ? 1 : 0;
        xproj_mfma<<<dim3((hasA + hasB) * 64 * xg), dim3(256), 0, stream>>>(
            hasA, xs, wxp0, b0, xp0, s * C,
            out, wxp1, b1, xp1, (s - 1) * C, C);
        if (hasA && hasB)
            lstm_recur2<<<dim3(128), dim3(768), 0, stream>>>(
                xp0, whp0, st0, s * C, xp1, whp1, st1, (s - 1) * C, out, C);
        else if (hasA)
            lstm_recur2<<<dim3(64), dim3(768), 0, stream>>>(
                xp0, whp0, st0, s * C, xp0, whp0, st0, 0, out, C);
        else
            lstm_recur2<<<dim3(64), dim3(768), 0, stream>>>(
                xp1, whp1, st1, (s - 1) * C, xp1, whp1, st1, 0, out, C);
    }
}